// Round 8
// baseline (85.833 us; speedup 1.0000x reference)
//
#include <hip/hip_runtime.h>
#include <math.h>

#define NO_CH   144      // 4*16 + 80
#define NC      80
#define REGMAX  16
#define A_TOT   8400     // 80*80 + 40*40 + 20*20
#define HW0     6400
#define HW1     1600
#define HW2     400
#define SC_BLOCKS 132    // 64-anchor tiles; levels are 64-aligned

typedef float f32x4 __attribute__((ext_vector_type(4)));

__device__ __forceinline__ float rcpf(float x) { return __builtin_amdgcn_rcpf(x); }
__device__ __forceinline__ float sigmoidf(float x) {
    return rcpf(1.0f + __expf(-x));
}

// ---------------------------------------------------------------------------
// R7 structure + hoisted loads (MLP fix).
//  one block = 64 anchors of one batch; boxes (DFL) + scores.
//  FAST PATH (full tile): all 9 float4 loads issued back-to-back up front
//  (4 DFL + 5 score rows -> 9 in-flight loads/wave instead of 4 then 5
//  separated by the exp dependency chain), then compute:
//    phase 1: wave=group butterfly DFL -> dist_lds (1KB)
//    phase 2: sigmoid -> LDS tile [80][65]
//  single barrier; boxes 1KB contiguous; scores f32x4 column-read stores.
//  Lesson R6: transposed output must leave as full lines (keep LDS tile).
// ---------------------------------------------------------------------------
__global__ __launch_bounds__(256, 6) void fused_kernel(
    const float* __restrict__ f0, const float* __restrict__ f1,
    const float* __restrict__ f2, float* __restrict__ out_boxes,
    float* __restrict__ out_scores)
{
    __shared__ float tile[NC][65];     // 20.8 KB
    __shared__ float dist_lds[4][64];  // 1 KB

    const int b   = blockIdx.y;
    const int a0  = blockIdx.x * 64;
    const int tid = threadIdx.x;

    const float* base; int hw, local; float st;
    if (a0 < HW0) {
        base = f0 + (size_t)b * NO_CH * HW0; hw = HW0; local = a0; st = 8.0f;
    } else if (a0 < HW0 + HW1) {
        base = f1 + (size_t)b * NO_CH * HW1; hw = HW1; local = a0 - HW0; st = 16.0f;
    } else {
        base = f2 + (size_t)b * NO_CH * HW2; hw = HW2; local = a0 - HW0 - HW1; st = 32.0f;
    }

    const int nvalid = min(64, A_TOT - a0);

    if (nvalid == 64) {
        // ---------------- fast path: hoist all 9 loads ----------------
        const int g    = tid >> 6;       // wave = DFL group
        const int lane = tid & 63;
        const int laq  = lane & 15;      // anchor quad
        const int rq   = lane >> 4;      // channel quad (0..3)
        const int quad = tid & 15;       // phase-2 float4 slot
        const int r0   = tid >> 4;       // phase-2 row base (0..15)

        const float* s1  = base + (size_t)(g * REGMAX + rq * 4) * hw + local + laq * 4;
        const float* ssc = base + (size_t)(4 * REGMAX) * hw + local + quad * 4;

        float4 v[4];
        #pragma unroll
        for (int r = 0; r < 4; ++r)
            v[r] = *reinterpret_cast<const float4*>(s1 + (size_t)r * hw);
        float4 u[5];
        #pragma unroll
        for (int i = 0; i < 5; ++i)
            u[i] = *reinterpret_cast<const float4*>(ssc + (size_t)(r0 + 16 * i) * hw);

        // ---- phase 1 compute: no-max exp + butterfly over channel quads ----
        float4 se = make_float4(0.f, 0.f, 0.f, 0.f);
        float4 sw = make_float4(0.f, 0.f, 0.f, 0.f);
        #pragma unroll
        for (int r = 0; r < 4; ++r) {
            const float wgt = (float)(rq * 4 + r);
            const float ex = __expf(v[r].x);
            const float ey = __expf(v[r].y);
            const float ez = __expf(v[r].z);
            const float ew = __expf(v[r].w);
            se.x += ex; se.y += ey; se.z += ez; se.w += ew;
            sw.x += ex * wgt; sw.y += ey * wgt; sw.z += ez * wgt; sw.w += ew * wgt;
        }
        #pragma unroll
        for (int m = 16; m <= 32; m <<= 1) {
            se.x += __shfl_xor(se.x, m, 64);
            se.y += __shfl_xor(se.y, m, 64);
            se.z += __shfl_xor(se.z, m, 64);
            se.w += __shfl_xor(se.w, m, 64);
            sw.x += __shfl_xor(sw.x, m, 64);
            sw.y += __shfl_xor(sw.y, m, 64);
            sw.z += __shfl_xor(sw.z, m, 64);
            sw.w += __shfl_xor(sw.w, m, 64);
        }
        if (rq == 0) {
            const float4 dist = make_float4(sw.x * rcpf(se.x), sw.y * rcpf(se.y),
                                            sw.z * rcpf(se.z), sw.w * rcpf(se.w));
            *reinterpret_cast<float4*>(&dist_lds[g][laq * 4]) = dist;
        }

        // ---- phase 2 compute: sigmoid -> tile ----
        #pragma unroll
        for (int i = 0; i < 5; ++i) {
            const int r = r0 + 16 * i;
            tile[r][quad * 4 + 0] = sigmoidf(u[i].x);
            tile[r][quad * 4 + 1] = sigmoidf(u[i].y);
            tile[r][quad * 4 + 2] = sigmoidf(u[i].z);
            tile[r][quad * 4 + 3] = sigmoidf(u[i].w);
        }
    } else {
        // ---------------- tail tile (16 anchors): scalar path ----------------
        {
            const int g    = tid >> 6;
            const int lane = tid & 63;
            const int laq  = lane & 15;
            const int rq   = lane >> 4;

            float4 se = make_float4(0.f, 0.f, 0.f, 0.f);
            float4 sw = make_float4(0.f, 0.f, 0.f, 0.f);
            if (laq * 4 < nvalid) {
                const float* s = base + (size_t)(g * REGMAX + rq * 4) * hw + local + laq * 4;
                #pragma unroll
                for (int r = 0; r < 4; ++r) {
                    const float4 vv = *reinterpret_cast<const float4*>(s + (size_t)r * hw);
                    const float wgt = (float)(rq * 4 + r);
                    const float ex = __expf(vv.x);
                    const float ey = __expf(vv.y);
                    const float ez = __expf(vv.z);
                    const float ew = __expf(vv.w);
                    se.x += ex; se.y += ey; se.z += ez; se.w += ew;
                    sw.x += ex * wgt; sw.y += ey * wgt; sw.z += ez * wgt; sw.w += ew * wgt;
                }
            }
            #pragma unroll
            for (int m = 16; m <= 32; m <<= 1) {
                se.x += __shfl_xor(se.x, m, 64);
                se.y += __shfl_xor(se.y, m, 64);
                se.z += __shfl_xor(se.z, m, 64);
                se.w += __shfl_xor(se.w, m, 64);
                sw.x += __shfl_xor(sw.x, m, 64);
                sw.y += __shfl_xor(sw.y, m, 64);
                sw.z += __shfl_xor(sw.z, m, 64);
                sw.w += __shfl_xor(sw.w, m, 64);
            }
            if (rq == 0 && laq * 4 < nvalid) {
                const float4 dist = make_float4(sw.x * rcpf(se.x), sw.y * rcpf(se.y),
                                                sw.z * rcpf(se.z), sw.w * rcpf(se.w));
                *reinterpret_cast<float4*>(&dist_lds[g][laq * 4]) = dist;
            }
        }
        const float* ssc = base + (size_t)(4 * REGMAX) * hw + local;
        const int col = tid & 63;
        const int r0  = tid >> 6;
        if (col < nvalid) {
            #pragma unroll
            for (int i = 0; i < 20; ++i) {
                const int r = r0 + 4 * i;
                tile[r][col] = sigmoidf(ssc[(size_t)r * hw + col]);
            }
        }
    }

    __syncthreads();

    // ---- boxes out: 4*nvalid contiguous floats, one per thread ----
    if (tid < 4 * nvalid) {
        const int la   = tid >> 2;
        const int comp = tid & 3;
        const int gl   = local + la;
        int ix, iy;
        if (hw == HW0)      { iy = gl / 80; ix = gl - iy * 80; }
        else if (hw == HW1) { iy = gl / 40; ix = gl - iy * 40; }
        else                { iy = gl / 20; ix = gl - iy * 20; }
        const float axy = ((comp & 1) ? (float)iy : (float)ix) + 0.5f;
        const float d   = dist_lds[comp][la];
        const float val = (axy + ((comp >= 2) ? d : -d)) * st;
        __builtin_nontemporal_store(
            val, out_boxes + ((size_t)b * A_TOT + a0) * 4 + tid);
    }

    // ---- scores out: f32x4 stores, column reads from the tile ----
    float* dst = out_scores + ((size_t)b * A_TOT + a0) * NC;
    const int nq = nvalid * (NC / 4);          // 1280 (or 320 on tail tile)
    for (int j4 = tid; j4 < nq; j4 += 256) {
        const int la = j4 / 20;
        const int c0 = (j4 - la * 20) * 4;
        f32x4 o;
        o.x = tile[c0 + 0][la];
        o.y = tile[c0 + 1][la];
        o.z = tile[c0 + 2][la];
        o.w = tile[c0 + 3][la];
        __builtin_nontemporal_store(o, reinterpret_cast<f32x4*>(dst) + j4);
    }
}

extern "C" void kernel_launch(void* const* d_in, const int* in_sizes, int n_in,
                              void* d_out, int out_size, void* d_ws, size_t ws_size,
                              hipStream_t stream) {
    const float* f0 = (const float*)d_in[0];
    const float* f1 = (const float*)d_in[1];
    const float* f2 = (const float*)d_in[2];

    const int b = in_sizes[0] / (NO_CH * HW0);   // 64

    float* out_boxes  = (float*)d_out;
    float* out_scores = out_boxes + (size_t)b * A_TOT * 4;

    dim3 grid(SC_BLOCKS, b);
    fused_kernel<<<grid, dim3(256), 0, stream>>>(f0, f1, f2, out_boxes, out_scores);
}

// Round 9
// 84.813 us; speedup vs baseline: 1.0120x; 1.0120x over previous
//
#include <hip/hip_runtime.h>
#include <math.h>

#define NO_CH   144      // 4*16 + 80
#define NC      80
#define REGMAX  16
#define A_TOT   8400     // 80*80 + 40*40 + 20*20
#define HW0     6400
#define HW1     1600
#define HW2     400
#define SC_BLOCKS 132    // 64-anchor tiles; levels are 64-aligned

typedef float f32x4 __attribute__((ext_vector_type(4)));

__device__ __forceinline__ float rcpf(float x) { return __builtin_amdgcn_rcpf(x); }
__device__ __forceinline__ float sigmoidf(float x) {
    return rcpf(1.0f + __expf(-x));
}

// ---------------------------------------------------------------------------
// R8 + sched_barrier(0) after the 9-load burst.
//  R8 lesson: source-order hoisting was re-sunk by the scheduler (VGPR stayed
//  36 -> loads never went wide). The fence pins all 9 float4 loads above the
//  compute so the wave has 9 KB of reads in flight. DFL loads issue first so
//  the compiler can release the exp chain at vmcnt(5) while score loads fly.
//  launch_bounds min-waves relaxed 6->4 to give the allocator VGPR headroom
//  (LDS still caps at 7 blocks/CU, so occupancy should be unchanged).
// ---------------------------------------------------------------------------
__global__ __launch_bounds__(256, 4) void fused_kernel(
    const float* __restrict__ f0, const float* __restrict__ f1,
    const float* __restrict__ f2, float* __restrict__ out_boxes,
    float* __restrict__ out_scores)
{
    __shared__ float tile[NC][65];     // 20.8 KB
    __shared__ float dist_lds[4][64];  // 1 KB

    const int b   = blockIdx.y;
    const int a0  = blockIdx.x * 64;
    const int tid = threadIdx.x;

    const float* base; int hw, local; float st;
    if (a0 < HW0) {
        base = f0 + (size_t)b * NO_CH * HW0; hw = HW0; local = a0; st = 8.0f;
    } else if (a0 < HW0 + HW1) {
        base = f1 + (size_t)b * NO_CH * HW1; hw = HW1; local = a0 - HW0; st = 16.0f;
    } else {
        base = f2 + (size_t)b * NO_CH * HW2; hw = HW2; local = a0 - HW0 - HW1; st = 32.0f;
    }

    const int nvalid = min(64, A_TOT - a0);

    if (nvalid == 64) {
        // ---------------- fast path ----------------
        const int g    = tid >> 6;       // wave = DFL group
        const int lane = tid & 63;
        const int laq  = lane & 15;      // anchor quad
        const int rq   = lane >> 4;      // channel quad (0..3)
        const int quad = tid & 15;       // phase-2 float4 slot
        const int r0   = tid >> 4;       // phase-2 row base (0..15)

        const float* s1  = base + (size_t)(g * REGMAX + rq * 4) * hw + local + laq * 4;
        const float* ssc = base + (size_t)(4 * REGMAX) * hw + local + quad * 4;

        // 9-load burst: DFL first, then scores
        float4 v[4];
        #pragma unroll
        for (int r = 0; r < 4; ++r)
            v[r] = *reinterpret_cast<const float4*>(s1 + (size_t)r * hw);
        float4 u[5];
        #pragma unroll
        for (int i = 0; i < 5; ++i)
            u[i] = *reinterpret_cast<const float4*>(ssc + (size_t)(r0 + 16 * i) * hw);

        // fence: loads may not be sunk below this point
        __builtin_amdgcn_sched_barrier(0);

        // ---- phase 1 compute: no-max exp + butterfly over channel quads ----
        float4 se = make_float4(0.f, 0.f, 0.f, 0.f);
        float4 sw = make_float4(0.f, 0.f, 0.f, 0.f);
        #pragma unroll
        for (int r = 0; r < 4; ++r) {
            const float wgt = (float)(rq * 4 + r);
            const float ex = __expf(v[r].x);
            const float ey = __expf(v[r].y);
            const float ez = __expf(v[r].z);
            const float ew = __expf(v[r].w);
            se.x += ex; se.y += ey; se.z += ez; se.w += ew;
            sw.x += ex * wgt; sw.y += ey * wgt; sw.z += ez * wgt; sw.w += ew * wgt;
        }
        #pragma unroll
        for (int m = 16; m <= 32; m <<= 1) {
            se.x += __shfl_xor(se.x, m, 64);
            se.y += __shfl_xor(se.y, m, 64);
            se.z += __shfl_xor(se.z, m, 64);
            se.w += __shfl_xor(se.w, m, 64);
            sw.x += __shfl_xor(sw.x, m, 64);
            sw.y += __shfl_xor(sw.y, m, 64);
            sw.z += __shfl_xor(sw.z, m, 64);
            sw.w += __shfl_xor(sw.w, m, 64);
        }
        if (rq == 0) {
            const float4 dist = make_float4(sw.x * rcpf(se.x), sw.y * rcpf(se.y),
                                            sw.z * rcpf(se.z), sw.w * rcpf(se.w));
            *reinterpret_cast<float4*>(&dist_lds[g][laq * 4]) = dist;
        }

        // ---- phase 2 compute: sigmoid -> tile ----
        #pragma unroll
        for (int i = 0; i < 5; ++i) {
            const int r = r0 + 16 * i;
            tile[r][quad * 4 + 0] = sigmoidf(u[i].x);
            tile[r][quad * 4 + 1] = sigmoidf(u[i].y);
            tile[r][quad * 4 + 2] = sigmoidf(u[i].z);
            tile[r][quad * 4 + 3] = sigmoidf(u[i].w);
        }
    } else {
        // ---------------- tail tile (16 anchors) ----------------
        {
            const int g    = tid >> 6;
            const int lane = tid & 63;
            const int laq  = lane & 15;
            const int rq   = lane >> 4;

            float4 se = make_float4(0.f, 0.f, 0.f, 0.f);
            float4 sw = make_float4(0.f, 0.f, 0.f, 0.f);
            if (laq * 4 < nvalid) {
                const float* s = base + (size_t)(g * REGMAX + rq * 4) * hw + local + laq * 4;
                #pragma unroll
                for (int r = 0; r < 4; ++r) {
                    const float4 vv = *reinterpret_cast<const float4*>(s + (size_t)r * hw);
                    const float wgt = (float)(rq * 4 + r);
                    const float ex = __expf(vv.x);
                    const float ey = __expf(vv.y);
                    const float ez = __expf(vv.z);
                    const float ew = __expf(vv.w);
                    se.x += ex; se.y += ey; se.z += ez; se.w += ew;
                    sw.x += ex * wgt; sw.y += ey * wgt; sw.z += ez * wgt; sw.w += ew * wgt;
                }
            }
            #pragma unroll
            for (int m = 16; m <= 32; m <<= 1) {
                se.x += __shfl_xor(se.x, m, 64);
                se.y += __shfl_xor(se.y, m, 64);
                se.z += __shfl_xor(se.z, m, 64);
                se.w += __shfl_xor(se.w, m, 64);
                sw.x += __shfl_xor(sw.x, m, 64);
                sw.y += __shfl_xor(sw.y, m, 64);
                sw.z += __shfl_xor(sw.z, m, 64);
                sw.w += __shfl_xor(sw.w, m, 64);
            }
            if (rq == 0 && laq * 4 < nvalid) {
                const float4 dist = make_float4(sw.x * rcpf(se.x), sw.y * rcpf(se.y),
                                                sw.z * rcpf(se.z), sw.w * rcpf(se.w));
                *reinterpret_cast<float4*>(&dist_lds[g][laq * 4]) = dist;
            }
        }
        const float* ssc = base + (size_t)(4 * REGMAX) * hw + local;
        const int col = tid & 63;
        const int r0  = tid >> 6;
        if (col < nvalid) {
            #pragma unroll
            for (int i = 0; i < 20; ++i) {
                const int r = r0 + 4 * i;
                tile[r][col] = sigmoidf(ssc[(size_t)r * hw + col]);
            }
        }
    }

    __syncthreads();

    // ---- boxes out: 4*nvalid contiguous floats, one per thread ----
    if (tid < 4 * nvalid) {
        const int la   = tid >> 2;
        const int comp = tid & 3;
        const int gl   = local + la;
        int ix, iy;
        if (hw == HW0)      { iy = gl / 80; ix = gl - iy * 80; }
        else if (hw == HW1) { iy = gl / 40; ix = gl - iy * 40; }
        else                { iy = gl / 20; ix = gl - iy * 20; }
        const float axy = ((comp & 1) ? (float)iy : (float)ix) + 0.5f;
        const float d   = dist_lds[comp][la];
        const float val = (axy + ((comp >= 2) ? d : -d)) * st;
        __builtin_nontemporal_store(
            val, out_boxes + ((size_t)b * A_TOT + a0) * 4 + tid);
    }

    // ---- scores out: f32x4 stores, column reads from the tile ----
    float* dst = out_scores + ((size_t)b * A_TOT + a0) * NC;
    const int nq = nvalid * (NC / 4);          // 1280 (or 320 on tail tile)
    for (int j4 = tid; j4 < nq; j4 += 256) {
        const int la = j4 / 20;
        const int c0 = (j4 - la * 20) * 4;
        f32x4 o;
        o.x = tile[c0 + 0][la];
        o.y = tile[c0 + 1][la];
        o.z = tile[c0 + 2][la];
        o.w = tile[c0 + 3][la];
        __builtin_nontemporal_store(o, reinterpret_cast<f32x4*>(dst) + j4);
    }
}

extern "C" void kernel_launch(void* const* d_in, const int* in_sizes, int n_in,
                              void* d_out, int out_size, void* d_ws, size_t ws_size,
                              hipStream_t stream) {
    const float* f0 = (const float*)d_in[0];
    const float* f1 = (const float*)d_in[1];
    const float* f2 = (const float*)d_in[2];

    const int b = in_sizes[0] / (NO_CH * HW0);   // 64

    float* out_boxes  = (float*)d_out;
    float* out_scores = out_boxes + (size_t)b * A_TOT * 4;

    dim3 grid(SC_BLOCKS, b);
    fused_kernel<<<grid, dim3(256), 0, stream>>>(f0, f1, f2, out_boxes, out_scores);
}